// Round 6
// baseline (246.706 us; speedup 1.0000x reference)
//
#include <hip/hip_runtime.h>
#include <hip/hip_bf16.h>

// Problem constants
#define NB 2
#define NL 2048
#define ND 1024
#define NH 16
#define NDH 64
#define NM (NB*NL)   // 4096 rows total

typedef unsigned short u16;
typedef __attribute__((ext_vector_type(8))) short short8;   // 8 bf16 in 4 VGPRs
typedef __attribute__((ext_vector_type(4))) float floatx4;  // MFMA accumulator

// fp32 -> bf16 round-to-nearest-even (bit trick)
__device__ __forceinline__ u16 f2bf(float f) {
  union { float f; unsigned int u; } v; v.f = f;
  unsigned int r = v.u + 0x7FFF + ((v.u >> 16) & 1);
  return (u16)(r >> 16);
}

// async global->LDS 16B (m97 lever). LDS dest is wave-uniform base + lane*16.
__device__ __forceinline__ void async_cp16(u16* lds, const u16* g) {
  __builtin_amdgcn_global_load_lds(
      (const __attribute__((address_space(1))) void*)g,
      (__attribute__((address_space(3))) void*)lds, 16, 0, 0);
}

// lane <-> lane^1 exchange on the VALU (DPP quad_perm [1,0,3,2]) — no LDS pipe
__device__ __forceinline__ unsigned dpp_xor1(unsigned v) {
  return (unsigned)__builtin_amdgcn_mov_dpp((int)v, 0xB1, 0xF, 0xF, true);
}

// ---------------------------------------------------------------------------
// Pre-convert fp32 -> bf16: Wq,Wk,Wv,Wp (1M elems each) -> Wb, x (4M) -> xb.
// ---------------------------------------------------------------------------
__global__ __launch_bounds__(256)
void cvt_all(const float* __restrict__ wq, const float* __restrict__ wk,
             const float* __restrict__ wv, const float* __restrict__ wp,
             const float* __restrict__ x,
             u16* __restrict__ ow, u16* __restrict__ ox)
{
  const int per4 = ND * ND / 4;            // 262144 float4 per weight matrix
  const int tot  = 4 * per4 + NM * ND / 4; // + 1048576 for x
  for (int t = blockIdx.x * 256 + threadIdx.x; t < tot; t += gridDim.x * 256) {
    const float* src; uint2* dst; int off;
    if (t < 4 * per4) {
      int w = t >> 18; off = t & (per4 - 1);
      src = (w == 0) ? wq : (w == 1) ? wk : (w == 2) ? wv : wp;
      dst = (uint2*)(ow + (size_t)w * ND * ND);
    } else {
      off = t - 4 * per4; src = x; dst = (uint2*)ox;
    }
    float4 f = ((const float4*)src)[off];
    u16 h[4] = { f2bf(f.x), f2bf(f.y), f2bf(f.z), f2bf(f.w) };
    dst[off] = *(const uint2*)h;
  }
}

// ---------------------------------------------------------------------------
// GEMM: C[m][n] = (sum_k A[m][k] * W[n][k] + bias[n]) * scale_z
// A,W: bf16, staged via async global_load_lds (m97 structure).
// C: fp32 or bf16. blockIdx.z selects weight/out set; scale0 applies to z==0.
// 128x128 tile, BK=32, 256 threads (4 waves as 2x2 of 64x64), MFMA 16x16x32.
// ---------------------------------------------------------------------------
#define BM 128
#define BN 128
#define BK 32
#define LDT 32   // LDS tile row stride in bf16 elems (contiguous for async cp)

template<bool C_F32>
__global__ __launch_bounds__(256)
void gemm_bt_bias(const u16* __restrict__ A,
                  const u16* __restrict__ W0, const u16* __restrict__ W1, const u16* __restrict__ W2,
                  const float* __restrict__ B0, const float* __restrict__ B1, const float* __restrict__ B2,
                  void* __restrict__ C0, void* __restrict__ C1, void* __restrict__ C2,
                  float scale0)
{
  const int z = blockIdx.z;
  const u16* W    = (z == 0) ? W0 : (z == 1) ? W1 : W2;
  const float* Bi = (z == 0) ? B0 : (z == 1) ? B1 : B2;
  void* C         = (z == 0) ? C0 : (z == 1) ? C1 : C2;
  const float sc  = (z == 0) ? scale0 : 1.0f;

  const int n0 = blockIdx.x * BN;
  const int m0 = blockIdx.y * BM;
  const int tid  = threadIdx.x;
  const int lane = tid & 63;
  const int wave = tid >> 6;
  const int wm = (wave >> 1) * 64;
  const int wn = (wave & 1) * 64;
  const int quad = lane >> 4;
  const int l16  = lane & 15;

  __shared__ u16 As[BM * LDT];
  __shared__ u16 Bs[BN * LDT];

  floatx4 acc[4][4];
#pragma unroll
  for (int i = 0; i < 4; ++i)
#pragma unroll
    for (int j = 0; j < 4; ++j)
      acc[i][j] = (floatx4){0.f, 0.f, 0.f, 0.f};

  for (int k0 = 0; k0 < ND; k0 += BK) {
#pragma unroll
    for (int it = 0; it < 2; ++it) {
      int idx = tid + it * 256;            // 0..511
      int rr  = idx >> 2;                  // 0..127
      int c8  = (idx & 3) << 3;            // 0,8,16,24
      async_cp16(&Bs[idx * 8], &W[(size_t)(n0 + rr) * ND + k0 + c8]);
      async_cp16(&As[idx * 8], &A[(size_t)(m0 + rr) * ND + k0 + c8]);
    }
    __syncthreads();

    short8 af[4], bfr[4];
#pragma unroll
    for (int i = 0; i < 4; ++i)
      af[i] = *(const short8*)&As[(wm + i * 16 + l16) * LDT + quad * 8];
#pragma unroll
    for (int j = 0; j < 4; ++j)
      bfr[j] = *(const short8*)&Bs[(wn + j * 16 + l16) * LDT + quad * 8];

#pragma unroll
    for (int i = 0; i < 4; ++i)
#pragma unroll
      for (int j = 0; j < 4; ++j)
        acc[i][j] = __builtin_amdgcn_mfma_f32_16x16x32_bf16(af[i], bfr[j], acc[i][j], 0, 0, 0);
    __syncthreads();
  }

  // Epilogue. D map: row=(lane>>4)*4+r, col=lane&15.
#pragma unroll
  for (int j = 0; j < 4; ++j) {
    const int ncol = n0 + wn + j * 16 + l16;
    const float bv = Bi[ncol];
#pragma unroll
    for (int i = 0; i < 4; ++i) {
      const int mbase = m0 + wm + i * 16 + quad * 4;
#pragma unroll
      for (int r2 = 0; r2 < 4; ++r2) {
        float v = (acc[i][j][r2] + bv) * sc;
        if (C_F32) ((float*)C)[(size_t)(mbase + r2) * ND + ncol] = v;
        else       ((u16*)C)[(size_t)(mbase + r2) * ND + ncol] = f2bf(v);
      }
    }
  }
}

// ---------------------------------------------------------------------------
// MFMA flash attention, no-max softmax, 32 q-rows per wave (rb=2).
// Block = 256 threads (4 waves), one (b,h), 128-row Q tile; wave owns 32 rows.
// K/V fragment LDS reads are shared across both row-blocks (2x amortization
// vs r5). P written to LDS as packed b32 via DPP lane-pair exchange.
// l via MFMA with ones B-fragment. Y aliases Q (wave reads its Q first,
// writes the same rows last).
// ---------------------------------------------------------------------------
#define KC 64
#define PSTR 72   // padded LDS row stride (bf16): 36 dwords -> 2-way (free)

__global__ __launch_bounds__(256)
void attn_mfma(const u16* __restrict__ Q, const u16* __restrict__ K,
               const u16* __restrict__ V, const int* __restrict__ msk,
               u16* __restrict__ Y)
{
  const int qt = gridDim.x - 1 - blockIdx.x;  // big tiles dispatched first
  const int bh = blockIdx.y;
  const int b = bh >> 4;
  const int h = bh & 15;
  const int q0 = qt * 128;
  const int tid  = threadIdx.x;
  const int lane = tid & 63;
  const int wave = tid >> 6;
  const int wq   = wave * 32;      // wave's q-row offset in tile
  const int quad = lane >> 4;
  const int l16  = lane & 15;

  __shared__ u16 Ks[KC][PSTR];     // [key][dim]
  __shared__ u16 Vt[NDH][PSTR];    // [dim][key]
  __shared__ u16 Ps[128][PSTR];    // [q_local][key]
  __shared__ u16 Ms[NL];           // key-pad multiplier 0/1

  const int nchunks = 2 * qt + 2;

  // Stage mask multipliers (only the causally-reachable prefix)
  for (int j = tid; j < nchunks * KC; j += 256) Ms[j] = (u16)(msk[b * NL + j] ? 1 : 0);

  // Q fragments (A-layout: m=l16, k=quad*8+j), pre-scaled by 1/8 in GEMM1.
  short8 qf[2][2];
#pragma unroll
  for (int rb = 0; rb < 2; ++rb)
#pragma unroll
    for (int kk = 0; kk < 2; ++kk)
      qf[rb][kk] = *(const short8*)&Q[(size_t)(b * NL + q0 + wq + rb * 16 + l16) * ND
                                      + h * NDH + kk * 32 + quad * 8];

  // Constant ones B-fragment: B[n=l16][k] = (n==0) ? 1.0bf : 0
  short8 onesf;
  {
    const short ov = (l16 == 0) ? (short)0x3F80 : (short)0;
#pragma unroll
    for (int e = 0; e < 8; ++e) onesf[e] = ov;
  }

  floatx4 o[2][4];                 // output accum, un-normalized
#pragma unroll
  for (int rb = 0; rb < 2; ++rb)
#pragma unroll
    for (int ot = 0; ot < 4; ++ot) o[rb][ot] = (floatx4){0.f, 0.f, 0.f, 0.f};
  floatx4 lacc[2];                 // col 0 holds row-sum l
  lacc[0] = (floatx4){0.f, 0.f, 0.f, 0.f};
  lacc[1] = (floatx4){0.f, 0.f, 0.f, 0.f};

  for (int kc = 0; kc < nchunks; ++kc) {
    const int k0 = kc * KC;

    // ---- stage K (natural, b128) ----
#pragma unroll
    for (int p = 0; p < 2; ++p) {
      int idx = tid + p * 256;       // 0..511
      int r = idx >> 3, c = (idx & 7) << 3;
      *(uint4*)&Ks[r][c] = *(const uint4*)&K[(size_t)(b * NL + k0 + r) * ND + h * NDH + c];
    }
    // ---- stage V transposed (paired rows -> b32 writes) ----
    {
      int rv = (tid & 31) * 2;        // 0,2,...,62
      int c  = (tid >> 5) * 8;        // 0,8,...,56
      uint4 va = *(const uint4*)&V[(size_t)(b * NL + k0 + rv)     * ND + h * NDH + c];
      uint4 vb = *(const uint4*)&V[(size_t)(b * NL + k0 + rv + 1) * ND + h * NDH + c];
      const u16* ap = (const u16*)&va;
      const u16* bp = (const u16*)&vb;
#pragma unroll
      for (int e = 0; e < 8; ++e)
        *(unsigned int*)&Vt[c + e][rv] = (unsigned int)ap[e] | ((unsigned int)bp[e] << 16);
    }
    __syncthreads();

    // ---- S = Q K^T  (C-layout: row=rb*16+quad*4+r2, col=ct*16+l16) ----
    floatx4 s[2][4];
#pragma unroll
    for (int ct = 0; ct < 4; ++ct) {
      short8 kf0 = *(const short8*)&Ks[ct * 16 + l16][quad * 8];
      short8 kf1 = *(const short8*)&Ks[ct * 16 + l16][32 + quad * 8];
#pragma unroll
      for (int rb = 0; rb < 2; ++rb) {
        floatx4 a = (floatx4){0.f, 0.f, 0.f, 0.f};
        a = __builtin_amdgcn_mfma_f32_16x16x32_bf16(qf[rb][0], kf0, a, 0, 0, 0);
        a = __builtin_amdgcn_mfma_f32_16x16x32_bf16(qf[rb][1], kf1, a, 0, 0, 0);
        s[rb][ct] = a;
      }
    }

    // ---- P = pad * causal * exp(S); packed b32 writes into LDS ----
    float pmul[4]; int col[4];
#pragma unroll
    for (int ct = 0; ct < 4; ++ct) {
      col[ct]  = k0 + ct * 16 + l16;
      pmul[ct] = (float)Ms[col[ct]];
    }
    const bool causal = (kc >= 2 * qt);   // block-uniform; last two chunks
    const int odd  = l16 & 1;
#pragma unroll
    for (int rb = 0; rb < 2; ++rb) {
      const int rowb = q0 + wq + rb * 16 + quad * 4;   // global row of r2=0
#pragma unroll
      for (int ct = 0; ct < 4; ++ct) {
        unsigned bb[4];
#pragma unroll
        for (int r2 = 0; r2 < 4; ++r2) {
          float p = pmul[ct] * __expf(s[rb][ct][r2]);
          if (causal) p = (col[ct] > rowb + r2) ? 0.f : p;
          bb[r2] = (unsigned)f2bf(p);
        }
        unsigned n0v = dpp_xor1(bb[0]), n1v = dpp_xor1(bb[1]);
        unsigned n2v = dpp_xor1(bb[2]), n3v = dpp_xor1(bb[3]);
        const int colb = ct * 16 + (l16 & ~1);
        const int row01 = wq + rb * 16 + quad * 4 + odd;   // r2=0 even / r2=1 odd
        unsigned d01 = odd ? (n1v | (bb[1] << 16)) : (bb[0] | (n0v << 16));
        unsigned d23 = odd ? (n3v | (bb[3] << 16)) : (bb[2] | (n2v << 16));
        *(unsigned*)&Ps[row01][colb]     = d01;
        *(unsigned*)&Ps[row01 + 2][colb] = d23;
      }
    }

    // ---- O += P V ; l += P * ones  (V frags shared across rb) ----
#pragma unroll
    for (int kk = 0; kk < 2; ++kk) {
      short8 pf[2];
#pragma unroll
      for (int rb = 0; rb < 2; ++rb)
        pf[rb] = *(const short8*)&Ps[wq + rb * 16 + l16][kk * 32 + quad * 8];
#pragma unroll
      for (int ot = 0; ot < 4; ++ot) {
        short8 vf = *(const short8*)&Vt[ot * 16 + l16][kk * 32 + quad * 8];
#pragma unroll
        for (int rb = 0; rb < 2; ++rb)
          o[rb][ot] = __builtin_amdgcn_mfma_f32_16x16x32_bf16(pf[rb], vf, o[rb][ot], 0, 0, 0);
      }
      lacc[0] = __builtin_amdgcn_mfma_f32_16x16x32_bf16(pf[0], onesf, lacc[0], 0, 0, 0);
      lacc[1] = __builtin_amdgcn_mfma_f32_16x16x32_bf16(pf[1], onesf, lacc[1], 0, 0, 0);
    }
    __syncthreads();   // protect Ks/Vt before restaging
  }

  // ---- epilogue: O / l -> Y (aliases Q; our rows only, reads done) ----
#pragma unroll
  for (int rb = 0; rb < 2; ++rb) {
    float inv[4];
#pragma unroll
    for (int r2 = 0; r2 < 4; ++r2) {
      const float l = __shfl(lacc[rb][r2], quad << 4);   // col 0 of the l-tile
      inv[r2] = 1.0f / l;
    }
#pragma unroll
    for (int ot = 0; ot < 4; ++ot)
#pragma unroll
      for (int r2 = 0; r2 < 4; ++r2) {
        const int row = q0 + wq + rb * 16 + quad * 4 + r2;
        Y[(size_t)(b * NL + row) * ND + h * NDH + ot * 16 + l16] =
            f2bf(o[rb][ot][r2] * inv[r2]);
      }
  }
}

// ---------------------------------------------------------------------------
extern "C" void kernel_launch(void* const* d_in, const int* in_sizes, int n_in,
                              void* d_out, int out_size, void* d_ws, size_t ws_size,
                              hipStream_t stream) {
  const float* x  = (const float*)d_in[0];
  const int*   m  = (const int*)d_in[1];
  const float* Wq = (const float*)d_in[2];
  const float* bq = (const float*)d_in[3];
  const float* Wk = (const float*)d_in[4];
  const float* bk = (const float*)d_in[5];
  const float* Wv = (const float*)d_in[6];
  const float* bv = (const float*)d_in[7];
  const float* Wp = (const float*)d_in[8];
  const float* bp = (const float*)d_in[9];
  float* out = (float*)d_out;

  // Workspace (32 MiB): Q|Y alias (8) + K (8) + V (8) + Wb bf16 x4 (8)
  // xb (bf16 x, 8 MiB) lives in d_out: read only by GEMM1, clobbered only by
  // the final proj GEMM (sequentially after).
  const size_t per = (size_t)NM * ND;
  u16* Qb = (u16*)d_ws;
  u16* Kb = Qb + per;
  u16* Vb = Kb + per;
  u16* Wb = Vb + per;              // 4 * ND*ND bf16, contiguous
  u16* Yb = Qb;                    // alias
  u16* xb = (u16*)d_out;

  // 0) fp32 -> bf16 for weights and x
  cvt_all<<<2048, 256, 0, stream>>>(Wq, Wk, Wv, Wp, x, Wb, xb);

  // 1) QKV projections (all-bf16 async staging; Q pre-scaled by 1/8)
  dim3 gq(ND / BN, NM / BM, 3);
  gemm_bt_bias<false><<<gq, 256, 0, stream>>>(
      xb, Wb, Wb + (size_t)ND * ND, Wb + 2 * (size_t)ND * ND,
      bq, bk, bv, (void*)Qb, (void*)Kb, (void*)Vb, 0.125f);

  // 2) MFMA flash attention (Y aliases Q)
  attn_mfma<<<dim3(NL / 128, NB * NH), 256, 0, stream>>>(Qb, Kb, Vb, m, Yb);

  // 3) Output projection (A=Y bf16, C=fp32 d_out)
  dim3 gp(ND / BN, NM / BM, 1);
  const u16* Wpb = Wb + 3 * (size_t)ND * ND;
  gemm_bt_bias<true><<<gp, 256, 0, stream>>>(
      Yb, Wpb, Wpb, Wpb, bp, bp, bp,
      (void*)out, (void*)out, (void*)out, 1.0f);
}